// Round 1
// baseline (479.556 us; speedup 1.0000x reference)
//
#include <hip/hip_runtime.h>
#include <hip/hip_bf16.h>

#define NNODES 50000
#define IN_F   128
#define NH     4
#define OD     16
#define HD     64   // NH*OD
#define NEG    0.2f

// ---------------------------------------------------------------------------
// Kernel 1: ft = feat @ W  (N x 128 @ 128 x 64), fused el/er reductions.
// One wave (64 lanes) per node; 4 nodes per 256-thread block.
// W staged in LDS (32 KB), feat rows staged in LDS (2 KB).
// ---------------------------------------------------------------------------
__global__ __launch_bounds__(256) void fc_kernel(
    const float* __restrict__ feat, const float* __restrict__ W,
    const float* __restrict__ attn_l, const float* __restrict__ attn_r,
    float* __restrict__ ft, float* __restrict__ el, float* __restrict__ er,
    int n_nodes) {
  __shared__ float Wl[IN_F * HD];   // 32 KB
  __shared__ float fl[4][IN_F];     // 2 KB
  const int t = threadIdx.x;
  const int node0 = blockIdx.x * 4;

  for (int i = t; i < IN_F * HD; i += 256) Wl[i] = W[i];
  for (int i = t; i < 4 * IN_F; i += 256) {
    int n = node0 + (i >> 7);
    fl[i >> 7][i & 127] = (n < n_nodes) ? feat[n * IN_F + (i & 127)] : 0.f;
  }
  __syncthreads();

  const int local = t >> 6;     // node within block (== wave id)
  const int col   = t & 63;     // h*16 + d
  const int n     = node0 + local;

  float acc = 0.f;
  #pragma unroll 16
  for (int k = 0; k < IN_F; ++k) acc += fl[local][k] * Wl[k * HD + col];

  const int h = col >> 4;
  const int d = col & 15;
  float vl = acc * attn_l[h * OD + d];
  float vr = acc * attn_r[h * OD + d];
  #pragma unroll
  for (int off = 8; off > 0; off >>= 1) {
    vl += __shfl_down(vl, off, 16);
    vr += __shfl_down(vr, off, 16);
  }
  if (n < n_nodes) {
    ft[n * HD + col] = acc;
    if (d == 0) {
      el[n * NH + h] = vl;
      er[n * NH + h] = vr;
    }
  }
}

// ---------------------------------------------------------------------------
// Kernel 2: per-edge scores. expe[e][h] = exp(ew * leaky(el[src]+er[dst]));
// denom[dst][h] += expe (atomic). Max-subtraction omitted: cancels exactly
// in the softmax ratio, scores bounded ~|5| so exp is fp32-safe.
// ---------------------------------------------------------------------------
__global__ __launch_bounds__(256) void edge_score_kernel(
    const int* __restrict__ src, const int* __restrict__ dst,
    const float* __restrict__ ew, const float* __restrict__ el,
    const float* __restrict__ er, float* __restrict__ expe,
    float* __restrict__ denom, int E) {
  int e = blockIdx.x * 256 + threadIdx.x;
  if (e >= E) return;
  const int s = src[e], dd = dst[e];
  const float w = ew[e];
  const float4 l = *(const float4*)(el + s * 4);
  const float4 r = *(const float4*)(er + dd * 4);
  float sc[4] = {l.x + r.x, l.y + r.y, l.z + r.z, l.w + r.w};
  float4 ex;
  float* exp_ = &ex.x;
  #pragma unroll
  for (int h = 0; h < 4; ++h) {
    float v = sc[h] > 0.f ? sc[h] : NEG * sc[h];
    exp_[h] = expf(w * v);
    atomicAdd(denom + dd * 4 + h, exp_[h]);
  }
  *(float4*)(expe + e * 4) = ex;
}

// ---------------------------------------------------------------------------
// Kernel 3: weighted scatter. One wave per edge, lane = h*16+d.
// out[dst][col] += ft[src][col] * (expe[e][h] / denom[dst][h])
// ---------------------------------------------------------------------------
__global__ __launch_bounds__(256) void aggregate_kernel(
    const int* __restrict__ src, const int* __restrict__ dst,
    const float* __restrict__ ft, const float* __restrict__ expe,
    const float* __restrict__ denom, float* __restrict__ out, int E) {
  const int e = blockIdx.x * 4 + (threadIdx.x >> 6);
  if (e >= E) return;
  const int col = threadIdx.x & 63;
  const int h = col >> 4;
  const int s = src[e], dd = dst[e];
  const float a = expe[e * 4 + h] / denom[dd * 4 + h];
  atomicAdd(out + dd * HD + col, ft[s * HD + col] * a);
}

extern "C" void kernel_launch(void* const* d_in, const int* in_sizes, int n_in,
                              void* d_out, int out_size, void* d_ws, size_t ws_size,
                              hipStream_t stream) {
  const float* feat   = (const float*)d_in[0];
  const int*   src    = (const int*)d_in[1];
  const int*   dst    = (const int*)d_in[2];
  const float* ew     = (const float*)d_in[3];
  const float* W      = (const float*)d_in[4];
  const float* attn_l = (const float*)d_in[5];
  const float* attn_r = (const float*)d_in[6];
  float* out = (float*)d_out;

  const int n_nodes = in_sizes[0] / IN_F;   // 50000
  const int E       = in_sizes[1];          // 800000

  // workspace layout (floats)
  float* ws    = (float*)d_ws;
  float* ft    = ws;                         // n_nodes*64
  float* el    = ft + (size_t)n_nodes * HD;  // n_nodes*4
  float* er    = el + (size_t)n_nodes * NH;
  float* denom = er + (size_t)n_nodes * NH;
  float* expe  = denom + (size_t)n_nodes * NH;  // E*4

  hipMemsetAsync(d_out, 0, (size_t)out_size * sizeof(float), stream);
  hipMemsetAsync(denom, 0, (size_t)n_nodes * NH * sizeof(float), stream);

  fc_kernel<<<(n_nodes + 3) / 4, 256, 0, stream>>>(feat, W, attn_l, attn_r,
                                                   ft, el, er, n_nodes);
  edge_score_kernel<<<(E + 255) / 256, 256, 0, stream>>>(src, dst, ew, el, er,
                                                         expe, denom, E);
  aggregate_kernel<<<(E + 3) / 4, 256, 0, stream>>>(src, dst, ft, expe, denom,
                                                    out, E);
}

// Round 2
// 298.875 us; speedup vs baseline: 1.6045x; 1.6045x over previous
//
#include <hip/hip_runtime.h>
#include <hip/hip_bf16.h>

#define IN_F   128
#define NH     4
#define OD     16
#define HD     64     // NH*OD
#define NEG    0.2f
#define PADK   132    // 128+4: keeps Wt float4 16B-aligned (132*4B = 33*16B), banks clean

// ---------------------------------------------------------------------------
// Kernel 1: ft = feat @ W, fused el/er. Block = 256 thr = 4 waves, 16 nodes.
// W transposed into LDS (Wt[col][k], padded); each wave does 4 nodes so one
// Wt float4 read feeds 16 FMAs.
// ---------------------------------------------------------------------------
__global__ __launch_bounds__(256) void fc_kernel(
    const float* __restrict__ feat, const float* __restrict__ W,
    const float* __restrict__ attn_l, const float* __restrict__ attn_r,
    float* __restrict__ ft, float* __restrict__ el, float* __restrict__ er,
    int n_nodes) {
  __shared__ float Wt[HD * PADK];      // 33 KB, Wt[c*PADK+k] = W[k*64+c]
  __shared__ float4 fl4[16][IN_F / 4]; // 8 KB
  const int t = threadIdx.x;
  const int node0 = blockIdx.x * 16;

  for (int i = t; i < IN_F * HD; i += 256) {
    int k = i >> 6, c = i & 63;
    Wt[c * PADK + k] = W[i];
  }
  for (int i = t; i < 16 * (IN_F / 4); i += 256) {   // 512 float4s
    int nl = i >> 5, off = i & 31;
    int n = node0 + nl;
    fl4[nl][off] = (n < n_nodes) ? ((const float4*)(feat + (size_t)n * IN_F))[off]
                                 : make_float4(0.f, 0.f, 0.f, 0.f);
  }
  __syncthreads();

  const int wave = t >> 6;          // 0..3 -> nodes 4w..4w+3
  const int col  = t & 63;
  const float* wtp = &Wt[col * PADK];

  float acc[4] = {0.f, 0.f, 0.f, 0.f};
  #pragma unroll 8
  for (int kc = 0; kc < IN_F / 4; ++kc) {
    const float4 wv = *(const float4*)(wtp + kc * 4);
    #pragma unroll
    for (int j = 0; j < 4; ++j) {
      const float4 fv = fl4[wave * 4 + j][kc];
      acc[j] += wv.x * fv.x + wv.y * fv.y + wv.z * fv.z + wv.w * fv.w;
    }
  }

  const int h = col >> 4, d = col & 15;
  const float al = attn_l[h * OD + d];
  const float ar = attn_r[h * OD + d];
  #pragma unroll
  for (int j = 0; j < 4; ++j) {
    const int n = node0 + wave * 4 + j;
    if (n >= n_nodes) break;
    float vl = acc[j] * al, vr = acc[j] * ar;
    #pragma unroll
    for (int off = 8; off > 0; off >>= 1) {
      vl += __shfl_down(vl, off, 16);
      vr += __shfl_down(vr, off, 16);
    }
    ft[(size_t)n * HD + col] = acc[j];
    if (d == 0) {
      el[n * NH + h] = vl;
      er[n * NH + h] = vr;
    }
  }
}

// ---------------------------------------------------------------------------
// CSR build: histogram -> 3-kernel exclusive scan -> scatter (src,ew) sorted.
// ---------------------------------------------------------------------------
__global__ __launch_bounds__(256) void hist_kernel(
    const int* __restrict__ dst, int* __restrict__ deg, int E) {
  int e = blockIdx.x * 256 + threadIdx.x;
  if (e < E) atomicAdd(&deg[dst[e]], 1);
}

__global__ __launch_bounds__(256) void scan1_kernel(
    const int* __restrict__ deg, int* __restrict__ bsum, int N) {
  __shared__ int sv[256];
  int n = blockIdx.x * 256 + threadIdx.x;
  sv[threadIdx.x] = (n < N) ? deg[n] : 0;
  __syncthreads();
  for (int off = 128; off > 0; off >>= 1) {
    if (threadIdx.x < off) sv[threadIdx.x] += sv[threadIdx.x + off];
    __syncthreads();
  }
  if (threadIdx.x == 0) bsum[blockIdx.x] = sv[0];
}

__global__ __launch_bounds__(256) void scan2_kernel(
    const int* __restrict__ bsum, int* __restrict__ boff,
    int* __restrict__ row_start, int NB, int N) {
  __shared__ int sv[256];
  const int t = threadIdx.x;
  const int v = (t < NB) ? bsum[t] : 0;
  sv[t] = v;
  __syncthreads();
  for (int off = 1; off < 256; off <<= 1) {
    int x = (t >= off) ? sv[t - off] : 0;
    __syncthreads();
    sv[t] += x;
    __syncthreads();
  }
  if (t < NB) boff[t] = sv[t] - v;         // exclusive
  if (t == 255) row_start[N] = sv[255];    // == E
}

__global__ __launch_bounds__(256) void scan3_kernel(
    const int* __restrict__ deg, const int* __restrict__ boff,
    int* __restrict__ row_start, int* __restrict__ cursor, int N) {
  __shared__ int sv[256];
  const int t = threadIdx.x;
  const int n = blockIdx.x * 256 + t;
  const int v = (n < N) ? deg[n] : 0;
  sv[t] = v;
  __syncthreads();
  for (int off = 1; off < 256; off <<= 1) {
    int x = (t >= off) ? sv[t - off] : 0;
    __syncthreads();
    sv[t] += x;
    __syncthreads();
  }
  if (n < N) {
    int rs = boff[blockIdx.x] + sv[t] - v;
    row_start[n] = rs;
    cursor[n] = rs;
  }
}

__global__ __launch_bounds__(256) void scatter_kernel(
    const int* __restrict__ src, const int* __restrict__ dst,
    const float* __restrict__ ew, int* __restrict__ cursor,
    int* __restrict__ s_sorted, float* __restrict__ w_sorted, int E) {
  int e = blockIdx.x * 256 + threadIdx.x;
  if (e >= E) return;
  int pos = atomicAdd(&cursor[dst[e]], 1);
  s_sorted[pos] = src[e];
  w_sorted[pos] = ew[e];
}

// ---------------------------------------------------------------------------
// Fused aggregate: one wave per dst node, no atomics, single pass computes
// softmax denominator + weighted sum (max-subtraction cancels exactly).
// ---------------------------------------------------------------------------
__global__ __launch_bounds__(256) void aggregate_csr_kernel(
    const int* __restrict__ row_start, const int* __restrict__ s_sorted,
    const float* __restrict__ w_sorted, const float* __restrict__ el,
    const float* __restrict__ er, const float* __restrict__ ft,
    float* __restrict__ out, int N) {
  const int n = blockIdx.x * 4 + (threadIdx.x >> 6);
  if (n >= N) return;
  const int col = threadIdx.x & 63;
  const int h = col >> 4;
  const int start = row_start[n], end = row_start[n + 1];
  const float erh = er[n * NH + h];
  float acc = 0.f, den = 0.f;
  for (int i = start; i < end; ++i) {
    const int s = s_sorted[i];
    const float w = w_sorted[i];
    float sc = el[s * NH + h] + erh;
    sc = sc > 0.f ? sc : NEG * sc;
    const float p = __expf(w * sc);
    den += p;
    acc += p * ft[(size_t)s * HD + col];
  }
  out[(size_t)n * HD + col] = (end > start) ? acc / den : 0.f;
}

extern "C" void kernel_launch(void* const* d_in, const int* in_sizes, int n_in,
                              void* d_out, int out_size, void* d_ws, size_t ws_size,
                              hipStream_t stream) {
  const float* feat   = (const float*)d_in[0];
  const int*   src    = (const int*)d_in[1];
  const int*   dst    = (const int*)d_in[2];
  const float* ew     = (const float*)d_in[3];
  const float* W      = (const float*)d_in[4];
  const float* attn_l = (const float*)d_in[5];
  const float* attn_r = (const float*)d_in[6];
  float* out = (float*)d_out;

  const int N  = in_sizes[0] / IN_F;   // 50000
  const int E  = in_sizes[1];          // 800000
  const int NB = (N + 255) / 256;      // 196

  // workspace layout
  char* p = (char*)d_ws;
  float* ft        = (float*)p;  p += (size_t)N * HD * 4;
  float* el        = (float*)p;  p += (size_t)N * NH * 4;
  float* er        = (float*)p;  p += (size_t)N * NH * 4;
  int*   deg       = (int*)p;    p += (size_t)N * 4;
  int*   row_start = (int*)p;    p += ((size_t)N + 1) * 4;
  int*   cursor    = (int*)p;    p += (size_t)N * 4;
  int*   bsum      = (int*)p;    p += 256 * 4;
  int*   boff      = (int*)p;    p += 256 * 4;
  int*   s_sorted  = (int*)p;    p += (size_t)E * 4;
  float* w_sorted  = (float*)p;  p += (size_t)E * 4;

  hipMemsetAsync(deg, 0, (size_t)N * 4, stream);

  fc_kernel<<<(N + 15) / 16, 256, 0, stream>>>(feat, W, attn_l, attn_r,
                                               ft, el, er, N);
  hist_kernel<<<(E + 255) / 256, 256, 0, stream>>>(dst, deg, E);
  scan1_kernel<<<NB, 256, 0, stream>>>(deg, bsum, N);
  scan2_kernel<<<1, 256, 0, stream>>>(bsum, boff, row_start, NB, N);
  scan3_kernel<<<NB, 256, 0, stream>>>(deg, boff, row_start, cursor, N);
  scatter_kernel<<<(E + 255) / 256, 256, 0, stream>>>(src, dst, ew, cursor,
                                                      s_sorted, w_sorted, E);
  aggregate_csr_kernel<<<(N + 3) / 4, 256, 0, stream>>>(row_start, s_sorted,
                                                        w_sorted, el, er, ft,
                                                        out, N);
}

// Round 3
// 250.817 us; speedup vs baseline: 1.9120x; 1.1916x over previous
//
#include <hip/hip_runtime.h>
#include <hip/hip_bf16.h>

#define IN_F   128
#define NH     4
#define OD     16
#define HD     64     // NH*OD
#define NEG    0.2f
#define PADK   132    // 128+4: keeps Wt float4 16B-aligned, banks clean
#define FCB    768    // fc blocks (persistent, 3/CU at 41KB LDS)

// ---------------------------------------------------------------------------
// Kernel 1 (fused): blocks [0,FCB) do ft = feat @ W + el/er (persistent,
// grid-stride over 16-node groups, W staged once per block). Blocks >= FCB
// do the dst-degree histogram (independent work, overlaps).
// ---------------------------------------------------------------------------
__global__ __launch_bounds__(256) void fc_hist_kernel(
    const float* __restrict__ feat, const float* __restrict__ W,
    const float* __restrict__ attn_l, const float* __restrict__ attn_r,
    __hip_bfloat16* __restrict__ ftb, float* __restrict__ el,
    float* __restrict__ er, const int* __restrict__ dst,
    int* __restrict__ deg, int n_nodes, int E) {
  const int t = threadIdx.x;

  if (blockIdx.x >= FCB) {               // ---- histogram part ----
    int e = (blockIdx.x - FCB) * 256 + t;
    if (e < E) atomicAdd(&deg[dst[e]], 1);
    return;
  }

  // ---- fc part ----
  __shared__ float Wt[HD * PADK];        // 33 KB, Wt[c*PADK+k] = W[k*64+c]
  __shared__ float4 fl4[16][IN_F / 4];   // 8 KB
  for (int i = t; i < IN_F * HD; i += 256) {
    int k = i >> 6, c = i & 63;
    Wt[c * PADK + k] = W[i];
  }

  const int wave = t >> 6;
  const int col  = t & 63;
  const int h = col >> 4, d = col & 15;
  const float al = attn_l[h * OD + d];
  const float ar = attn_r[h * OD + d];
  const float* wtp = &Wt[col * PADK];
  const int ngroups = (n_nodes + 15) / 16;

  for (int g = blockIdx.x; g < ngroups; g += FCB) {
    __syncthreads();                     // Wt ready (iter 0) / fl4 free (later)
    const int node0 = g * 16;
    for (int i = t; i < 16 * (IN_F / 4); i += 256) {
      int nl = i >> 5, off = i & 31;
      int n = node0 + nl;
      fl4[nl][off] = (n < n_nodes)
                         ? ((const float4*)(feat + (size_t)n * IN_F))[off]
                         : make_float4(0.f, 0.f, 0.f, 0.f);
    }
    __syncthreads();

    float acc[4] = {0.f, 0.f, 0.f, 0.f};
    #pragma unroll 8
    for (int kc = 0; kc < IN_F / 4; ++kc) {
      const float4 wv = *(const float4*)(wtp + kc * 4);
      #pragma unroll
      for (int j = 0; j < 4; ++j) {
        const float4 fv = fl4[wave * 4 + j][kc];
        acc[j] += wv.x * fv.x + wv.y * fv.y + wv.z * fv.z + wv.w * fv.w;
      }
    }

    #pragma unroll
    for (int j = 0; j < 4; ++j) {
      const int n = node0 + wave * 4 + j;
      if (n >= n_nodes) break;
      float vl = acc[j] * al, vr = acc[j] * ar;
      #pragma unroll
      for (int off = 8; off > 0; off >>= 1) {
        vl += __shfl_down(vl, off, 16);
        vr += __shfl_down(vr, off, 16);
      }
      ftb[(size_t)n * HD + col] = __float2bfloat16(acc[j]);
      if (d == 0) {
        el[n * NH + h] = vl;
        er[n * NH + h] = vr;
      }
    }
  }
}

// ---------------------------------------------------------------------------
// CSR build: 3-kernel exclusive scan over deg, then scatter (src,w) pairs.
// ---------------------------------------------------------------------------
__global__ __launch_bounds__(256) void scan1_kernel(
    const int* __restrict__ deg, int* __restrict__ bsum, int N) {
  __shared__ int sv[256];
  int n = blockIdx.x * 256 + threadIdx.x;
  sv[threadIdx.x] = (n < N) ? deg[n] : 0;
  __syncthreads();
  for (int off = 128; off > 0; off >>= 1) {
    if (threadIdx.x < off) sv[threadIdx.x] += sv[threadIdx.x + off];
    __syncthreads();
  }
  if (threadIdx.x == 0) bsum[blockIdx.x] = sv[0];
}

__global__ __launch_bounds__(256) void scan2_kernel(
    const int* __restrict__ bsum, int* __restrict__ boff,
    int* __restrict__ row_start, int NB, int N) {
  __shared__ int sv[256];
  const int t = threadIdx.x;
  const int v = (t < NB) ? bsum[t] : 0;
  sv[t] = v;
  __syncthreads();
  for (int off = 1; off < 256; off <<= 1) {
    int x = (t >= off) ? sv[t - off] : 0;
    __syncthreads();
    sv[t] += x;
    __syncthreads();
  }
  if (t < NB) boff[t] = sv[t] - v;
  if (t == 255) row_start[N] = sv[255];   // == E
}

__global__ __launch_bounds__(256) void scan3_kernel(
    const int* __restrict__ deg, const int* __restrict__ boff,
    int* __restrict__ row_start, int* __restrict__ cursor, int N) {
  __shared__ int sv[256];
  const int t = threadIdx.x;
  const int n = blockIdx.x * 256 + t;
  const int v = (n < N) ? deg[n] : 0;
  sv[t] = v;
  __syncthreads();
  for (int off = 1; off < 256; off <<= 1) {
    int x = (t >= off) ? sv[t - off] : 0;
    __syncthreads();
    sv[t] += x;
    __syncthreads();
  }
  if (n < N) {
    int rs = boff[blockIdx.x] + sv[t] - v;
    row_start[n] = rs;
    cursor[n] = rs;
  }
}

__global__ __launch_bounds__(256) void scatter_kernel(
    const int* __restrict__ src, const int* __restrict__ dst,
    const float* __restrict__ ew, int* __restrict__ cursor,
    int2* __restrict__ sw, int E) {
  int e = blockIdx.x * 256 + threadIdx.x;
  if (e >= E) return;
  int pos = atomicAdd(&cursor[dst[e]], 1);
  sw[pos] = make_int2(src[e], __float_as_int(ew[e]));
}

// ---------------------------------------------------------------------------
// Fused aggregate, MLP-restructured: lanes 0..7 batch-load 8 edges' (s,w),
// gather el float4 and compute all-head exp scores IN PARALLEL; shfl
// broadcast; unrolled j-loop issues 8 independent bf16 ft gathers.
// ---------------------------------------------------------------------------
__global__ __launch_bounds__(256) void aggregate_csr_kernel(
    const int* __restrict__ row_start, const int2* __restrict__ sw,
    const float* __restrict__ el, const float* __restrict__ er,
    const __hip_bfloat16* __restrict__ ftb, float* __restrict__ out, int N) {
  const int n = blockIdx.x * 4 + (threadIdx.x >> 6);
  if (n >= N) return;
  const int lane = threadIdx.x & 63;     // == output col
  const int h = lane >> 4;
  const int start = row_start[n], end = row_start[n + 1];
  const float4 er4 = *(const float4*)(er + n * 4);

  float acc = 0.f, den = 0.f;
  for (int i0 = start; i0 < end; i0 += 8) {
    const int m = min(8, end - i0);
    int sj = 0;
    float p0 = 0.f, p1 = 0.f, p2 = 0.f, p3 = 0.f;
    if (lane < m) {
      const int2 pr = sw[i0 + lane];
      sj = pr.x;
      const float w = __int_as_float(pr.y);
      const float4 l4 = *(const float4*)(el + sj * 4);
      float s0 = l4.x + er4.x, s1 = l4.y + er4.y;
      float s2 = l4.z + er4.z, s3 = l4.w + er4.w;
      s0 = s0 > 0.f ? s0 : NEG * s0;
      s1 = s1 > 0.f ? s1 : NEG * s1;
      s2 = s2 > 0.f ? s2 : NEG * s2;
      s3 = s3 > 0.f ? s3 : NEG * s3;
      p0 = __expf(w * s0);
      p1 = __expf(w * s1);
      p2 = __expf(w * s2);
      p3 = __expf(w * s3);
    }
    #pragma unroll
    for (int j = 0; j < 8; ++j) {
      if (j >= m) break;                 // wave-uniform
      const int s = __shfl(sj, j, 64);
      const float px = __shfl(p0, j, 64);
      const float py = __shfl(p1, j, 64);
      const float pz = __shfl(p2, j, 64);
      const float pw = __shfl(p3, j, 64);
      const float p = (h == 0) ? px : (h == 1) ? py : (h == 2) ? pz : pw;
      den += p;
      acc += p * (float)ftb[(size_t)s * HD + lane];
    }
  }
  out[(size_t)n * HD + lane] = (end > start) ? acc / den : 0.f;
}

extern "C" void kernel_launch(void* const* d_in, const int* in_sizes, int n_in,
                              void* d_out, int out_size, void* d_ws, size_t ws_size,
                              hipStream_t stream) {
  const float* feat   = (const float*)d_in[0];
  const int*   src    = (const int*)d_in[1];
  const int*   dst    = (const int*)d_in[2];
  const float* ew     = (const float*)d_in[3];
  const float* W      = (const float*)d_in[4];
  const float* attn_l = (const float*)d_in[5];
  const float* attn_r = (const float*)d_in[6];
  float* out = (float*)d_out;

  const int N  = in_sizes[0] / IN_F;   // 50000
  const int E  = in_sizes[1];          // 800000
  const int NB = (N + 255) / 256;      // 196

  // workspace layout (careful with 16B alignment for float4 el/er loads)
  char* p = (char*)d_ws;
  __hip_bfloat16* ftb = (__hip_bfloat16*)p; p += (size_t)N * HD * 2;  // 6.4MB, 16B-mult
  float* el        = (float*)p;  p += (size_t)N * NH * 4;             // 16B-mult
  float* er        = (float*)p;  p += (size_t)N * NH * 4;
  int2*  sw        = (int2*)p;   p += (size_t)E * 8;
  int*   deg       = (int*)p;    p += (size_t)N * 4;
  int*   row_start = (int*)p;    p += ((size_t)N + 2) * 4;
  int*   cursor    = (int*)p;    p += (size_t)N * 4;
  int*   bsum      = (int*)p;    p += 256 * 4;
  int*   boff      = (int*)p;    p += 256 * 4;

  hipMemsetAsync(deg, 0, (size_t)N * 4, stream);

  const int HB = (E + 255) / 256;      // histogram blocks
  fc_hist_kernel<<<FCB + HB, 256, 0, stream>>>(feat, W, attn_l, attn_r,
                                               ftb, el, er, dst, deg, N, E);
  scan1_kernel<<<NB, 256, 0, stream>>>(deg, bsum, N);
  scan2_kernel<<<1, 256, 0, stream>>>(bsum, boff, row_start, NB, N);
  scan3_kernel<<<NB, 256, 0, stream>>>(deg, boff, row_start, cursor, N);
  scatter_kernel<<<(E + 255) / 256, 256, 0, stream>>>(src, dst, ew, cursor,
                                                      sw, E);
  aggregate_csr_kernel<<<(N + 3) / 4, 256, 0, stream>>>(row_start, sw, el, er,
                                                        ftb, out, N);
}